// Round 15
// baseline (319.676 us; speedup 1.0000x reference)
//
#include <hip/hip_runtime.h>

typedef _Float16 h16;
typedef __attribute__((ext_vector_type(8))) _Float16 h16x8;
typedef __attribute__((ext_vector_type(4))) float f32x4;
typedef unsigned int u32;

#define BARRIER() __builtin_amdgcn_s_barrier()
#define VMCNT(n)  asm volatile("s_waitcnt vmcnt(" #n ")" ::: "memory")

// ------------- Kernel 1: fused aux = A fp32->fp16  +  2:4 int4 dequant -------
__global__ __launch_bounds__(256) void aux_kernel(const float* __restrict__ A,
    h16* __restrict__ Ah, int total8,
    const int* __restrict__ Bq, const int* __restrict__ meta,
    const float* __restrict__ s, h16* __restrict__ Wt,
    int K, int N, int chunksPerGroup, int nBlocksN) {
  const int bid = blockIdx.x;
  if (bid < 2048) {
    int stride = 2048 * 256;
    for (int i = bid * 256 + threadIdx.x; i < total8; i += stride) {
      const f32x4* p = (const f32x4*)(A + (size_t)i * 8);
      f32x4 v0 = p[0], v1 = p[1];
      h16x8 o;
      o[0] = (h16)v0[0]; o[1] = (h16)v0[1]; o[2] = (h16)v0[2]; o[3] = (h16)v0[3];
      o[4] = (h16)v1[0]; o[5] = (h16)v1[1]; o[6] = (h16)v1[2]; o[7] = (h16)v1[3];
      *(h16x8*)(Ah + (size_t)i * 8) = o;
    }
  } else {
    const int db = bid - 2048;
    const int n = (db % nBlocksN) * 256 + threadIdx.x;   // column of W
    const int chunk = db / nBlocksN;                     // 32 dense k rows
    u32 w0 = (u32)Bq[(size_t)(chunk * 2) * N + n];
    u32 w1 = (u32)Bq[(size_t)(chunk * 2 + 1) * N + n];
    float sc = s[(size_t)(chunk / chunksPerGroup) * N + n];
    h16 out[32];
#pragma unroll
    for (int gi = 0; gi < 8; ++gi) {
      int g = chunk * 8 + gi;
      int mm = meta[(size_t)g * N + n];
      u32 w = (gi < 4) ? w0 : w1;
      int j0 = (2 * gi) & 7;
      float d0 = (float)((int)((w >> (4 * j0)) & 0xFu) - 8) * sc;
      float d1 = (float)((int)((w >> (4 * j0 + 4)) & 0xFu) - 8) * sc;
      u32 enc = (0xED9C84u >> (4 * mm)) & 0xFu;
      int p0 = (int)(enc & 3u), p1 = (int)(enc >> 2);
#pragma unroll
      for (int p = 0; p < 4; ++p) {
        float v = (p == p0) ? d0 : ((p == p1) ? d1 : 0.0f);
        out[gi * 4 + p] = (h16)v;
      }
    }
    h16* dst = Wt + (size_t)n * K + chunk * 32;
    *(h16x8*)(dst + 0)  = *(h16x8*)(out + 0);
    *(h16x8*)(dst + 8)  = *(h16x8*)(out + 8);
    *(h16x8*)(dst + 16) = *(h16x8*)(out + 16);
    *(h16x8*)(dst + 24) = *(h16x8*)(out + 24);
  }
}

// ---------------- Kernel 2: GEMM, 2-blocks/CU convoy-free pipeline ----------
// R14's proven wave structure (64x64 wave tiles, counted vmcnt, same swizzle)
// but split into 512-thread blocks (8 waves 2Mx4N) computing 128x256 tiles,
// 3-slot LDS rotation (24 KiB/slot -> 72 KiB) => 2 independent blocks/CU at
// 4 waves/SIMD. Independent barriers let one block's read phase overlap the
// other block's MFMA phase (R14's single 1024-thread block serialized them:
// measured ~serial-sum cyc/tile). Distance-2 prefetch, 3 gloads/thread/tile,
// steady vmcnt(3) (retires stage(T+1)), tail vmcnt(0) at NT-2.
// Swizzle: LDS 16B-slot c of row r holds global chunk c ^ ((r>>1)&3);
// read slot = l16 ^ phi(row) -> uniform 2-way bank aliasing (free, m136).
__global__ __launch_bounds__(512, 4) void gemm_kernel(const h16* __restrict__ A,
    const h16* __restrict__ Wt, const float* __restrict__ bias,
    float* __restrict__ C, int M, int N, int K) {
  __shared__ alignas(16) h16 As[3][4096];   // [slot][128 rows x 32]  8 KiB
  __shared__ alignas(16) h16 Bs[3][8192];   // [slot][256 rows x 32] 16 KiB

  const int nTilesN = N >> 8;               // 256-wide N tiles
  const int nwg = gridDim.x;
  int bid = blockIdx.x;
  int wg = (bid & 7) * (nwg >> 3) + (bid >> 3);   // XCD swizzle (nwg%8==0)
  int tm = wg / nTilesN, tn = wg - tm * nTilesN;  // tm over M/128

  const int t = threadIdx.x;
  const int lane = t & 63, w = t >> 6;
  const int wr = w >> 2, wc = w & 3;        // 2M x 4N waves

  // ---- staging: A 1 gload/thread (rows 0-127), B 2 gloads (rows r, r+128) --
  const int srow = t >> 2;                  // 0..127
  const int chunk = (t & 3) ^ ((srow >> 1) & 3);
  const h16* gA_t = A + ((size_t)(tm * 128) + srow) * K + chunk * 8;
  const h16* gB_t = Wt + ((size_t)(tn * 256) + srow) * K + chunk * 8;
  const size_t rowK128 = (size_t)128 * K;   // +128 rows (phi unaffected by bit7)
  const int t8 = t * 8;

#define GLOAD(SRC, DST) __builtin_amdgcn_global_load_lds(                      \
    (const __attribute__((address_space(1))) void*)(SRC),                      \
    (__attribute__((address_space(3))) void*)(DST), 16, 0, 0)

#define STAGE(T_, SL_) do {                                                    \
    GLOAD(gA_t + (size_t)(T_) * 32, &As[SL_][t8]);                             \
    GLOAD(gB_t + (size_t)(T_) * 32, &Bs[SL_][t8]);                             \
    GLOAD(gB_t + rowK128 + (size_t)(T_) * 32, &Bs[SL_][t8 + 4096]);            \
  } while (0)

  // ---- fragment read offsets: slot = l16 ^ phi(row) ----
  const int ln15 = lane & 15, l16 = lane >> 4;
  const int slA = (l16 ^ ((ln15 >> 1) & 3)) * 8;
  const int aBase = (wr * 64 + ln15) * 32 + slA;    // A rows within [128]
  const int bBase = (wc * 64 + ln15) * 32 + slA;    // B rows within [256]

  f32x4 acc[4][4] = {};
  const int NT = K >> 5;

  // prologue: stage tiles 0,1 (distance 2); retire tile 0; publish.
  STAGE(0, 0); STAGE(1, 1);
  VMCNT(3);
  BARRIER();

  int sl = 0;
  for (int T = 0; T < NT; ++T) {
    const h16* aS = As[sl];
    const h16* bS = Bs[sl];
    h16x8 af[4], bf[4];
#pragma unroll
    for (int m = 0; m < 4; ++m) af[m] = *(const h16x8*)(aS + aBase + m * 512);
#pragma unroll
    for (int n = 0; n < 4; ++n) bf[n] = *(const h16x8*)(bS + bBase + n * 512);
    int sln = sl + 2; if (sln >= 3) sln -= 3;
    if (T + 2 < NT) STAGE(T + 2, sln);   // overwrites tile T-1's slot: reads done pre-barrier(T-1)
#pragma unroll
    for (int m = 0; m < 4; ++m)
#pragma unroll
      for (int n = 0; n < 4; ++n)
        acc[m][n] = __builtin_amdgcn_mfma_f32_16x16x32_f16(af[m], bf[n], acc[m][n], 0, 0, 0);
    // counted publish: retire stage(T+1) only; never drain in steady loop.
    if (T + 2 < NT) {
      VMCNT(3);
    } else if (T + 1 < NT) {
      VMCNT(0);
    }
    BARRIER();
    ++sl; if (sl == 3) sl = 0;
  }

  // ---- epilogue: col = ln15 (+n*16) from B side, row = l16*4+j (+m*16) ----
  int colBase = tn * 256 + wc * 64 + ln15;
  int rowBase = tm * 128 + wr * 64 + l16 * 4;
#pragma unroll
  for (int n = 0; n < 4; ++n) {
    float bv = bias[colBase + n * 16];
#pragma unroll
    for (int m = 0; m < 4; ++m) {
#pragma unroll
      for (int j = 0; j < 4; ++j) {
        C[(size_t)(rowBase + m * 16 + j) * N + colBase + n * 16] = acc[m][n][j] + bv;
      }
    }
  }
#undef STAGE
#undef GLOAD
}

extern "C" void kernel_launch(void* const* d_in, const int* in_sizes, int n_in,
                              void* d_out, int out_size, void* d_ws, size_t ws_size,
                              hipStream_t stream) {
  const float* A = (const float*)d_in[0];
  const int* Bq = (const int*)d_in[1];
  const int* meta = (const int*)d_in[2];
  const float* s = (const float*)d_in[3];
  const float* bias = (const float*)d_in[4];
  float* C = (float*)d_out;

  const int N = in_sizes[4];
  const int K = (int)(((long long)in_sizes[1] * 16) / N);
  const int M = (int)((long long)in_sizes[0] / K);
  const int sRows = (int)((long long)in_sizes[3] / N);       // K/GS
  const int chunksPerGroup = (K / sRows) / 32;               // GS/32
  const int nBlocksN = N / 256;

  h16* Ah = (h16*)d_ws;                       // M*K f16 = 64 MiB
  h16* Wt = Ah + (size_t)M * K;               // N*K f16 = 32 MiB (W^T, K-major)

  int auxGrid = 2048 + nBlocksN * (K / 32);
  aux_kernel<<<auxGrid, 256, 0, stream>>>(A, Ah, (M * K) / 8, Bq, meta, s, Wt,
                                          K, N, chunksPerGroup, nBlocksN);

  int grid = (M / 128) * (N / 256);
  gemm_kernel<<<grid, 512, 0, stream>>>(Ah, Wt, bias, C, M, N, K);
}

// Round 16
// 294.737 us; speedup vs baseline: 1.0846x; 1.0846x over previous
//
#include <hip/hip_runtime.h>

typedef _Float16 h16;
typedef __attribute__((ext_vector_type(8))) _Float16 h16x8;
typedef __attribute__((ext_vector_type(4))) float f32x4;
typedef unsigned int u32;

#define BARRIER() __builtin_amdgcn_s_barrier()
#define VMCNT(n)  asm volatile("s_waitcnt vmcnt(" #n ")" ::: "memory")

// ------------- Kernel 1: fused aux = A fp32->fp16  +  2:4 int4 dequant -------
__global__ __launch_bounds__(256) void aux_kernel(const float* __restrict__ A,
    h16* __restrict__ Ah, int total8,
    const int* __restrict__ Bq, const int* __restrict__ meta,
    const float* __restrict__ s, h16* __restrict__ Wt,
    int K, int N, int chunksPerGroup, int nBlocksN) {
  const int bid = blockIdx.x;
  if (bid < 2048) {
    int stride = 2048 * 256;
    for (int i = bid * 256 + threadIdx.x; i < total8; i += stride) {
      const f32x4* p = (const f32x4*)(A + (size_t)i * 8);
      f32x4 v0 = p[0], v1 = p[1];
      h16x8 o;
      o[0] = (h16)v0[0]; o[1] = (h16)v0[1]; o[2] = (h16)v0[2]; o[3] = (h16)v0[3];
      o[4] = (h16)v1[0]; o[5] = (h16)v1[1]; o[6] = (h16)v1[2]; o[7] = (h16)v1[3];
      *(h16x8*)(Ah + (size_t)i * 8) = o;
    }
  } else {
    const int db = bid - 2048;
    const int n = (db % nBlocksN) * 256 + threadIdx.x;   // column of W
    const int chunk = db / nBlocksN;                     // 32 dense k rows
    u32 w0 = (u32)Bq[(size_t)(chunk * 2) * N + n];
    u32 w1 = (u32)Bq[(size_t)(chunk * 2 + 1) * N + n];
    float sc = s[(size_t)(chunk / chunksPerGroup) * N + n];
    h16 out[32];
#pragma unroll
    for (int gi = 0; gi < 8; ++gi) {
      int g = chunk * 8 + gi;
      int mm = meta[(size_t)g * N + n];
      u32 w = (gi < 4) ? w0 : w1;
      int j0 = (2 * gi) & 7;
      float d0 = (float)((int)((w >> (4 * j0)) & 0xFu) - 8) * sc;
      float d1 = (float)((int)((w >> (4 * j0 + 4)) & 0xFu) - 8) * sc;
      u32 enc = (0xED9C84u >> (4 * mm)) & 0xFu;
      int p0 = (int)(enc & 3u), p1 = (int)(enc >> 2);
#pragma unroll
      for (int p = 0; p < 4; ++p) {
        float v = (p == p0) ? d0 : ((p == p1) ? d1 : 0.0f);
        out[gi * 4 + p] = (h16)v;
      }
    }
    h16* dst = Wt + (size_t)n * K + chunk * 32;
    *(h16x8*)(dst + 0)  = *(h16x8*)(out + 0);
    *(h16x8*)(dst + 8)  = *(h16x8*)(out + 8);
    *(h16x8*)(dst + 16) = *(h16x8*)(out + 16);
    *(h16x8*)(dst + 24) = *(h16x8*)(out + 24);
  }
}

// ---------------- Kernel 2: GEMM, 2-tile super-iteration pipeline ----------
// R14 geometry (256x256 tile, BK=32, 1024 thr = 16 waves 4Mx4N, 64x64/wave,
// 4-slot 128 KiB LDS, same swizzle) but ONE barrier per 2 K-tiles:
//   super(T): stage(T+2), stage(T+3)     <- top-of-super issue
//             {read T | mfma T}          <- no barrier inside:
//             {read T+1 | mfma T+1}         fast waves read T+1 while slow
//             vmcnt(0); barrier             waves mfma T -> LDS/MFMA overlap
// Slot audit: reads use slots T&3,(T+1)&3; stages fill (T+2)&3,(T+3)&3 (all
// distinct); overwritten tiles were read last super (pre-barrier). The end
// vmcnt(0) is ~5600 cyc after issue (L2-serviced ~600-900) -> nearly free,
// unlike R13's mid-tile drain. Swizzle: LDS slot c of row r holds chunk
// c ^ ((r>>1)&3); read slot = l16 ^ phi(row) -> uniform 2-way (free, m136).
__global__ __launch_bounds__(1024, 4) void gemm_kernel(const h16* __restrict__ A,
    const h16* __restrict__ Wt, const float* __restrict__ bias,
    float* __restrict__ C, int M, int N, int K) {
  __shared__ alignas(16) h16 As[4][8192];
  __shared__ alignas(16) h16 Bs[4][8192];

  const int nTilesN = N >> 8;
  const int nwg = gridDim.x;
  int bid = blockIdx.x;
  int wg = (bid & 7) * (nwg >> 3) + (bid >> 3);   // XCD swizzle (nwg%8==0)
  int tm = wg / nTilesN, tn = wg - tm * nTilesN;

  const int t = threadIdx.x;
  const int lane = t & 63, w = t >> 6;
  const int wr = w >> 2, wc = w & 3;

  // ---- staging: thread t covers LDS 16B-slot t; row=t>>2, dest col c=t&3
  // holds global chunk c ^ phi(row), phi(r) = (r>>1)&3 ----
  const int srow = t >> 2;
  const int chunk = (t & 3) ^ ((srow >> 1) & 3);
  const h16* gA_t = A + ((size_t)(tm * 256) + srow) * K + chunk * 8;
  const h16* gB_t = Wt + ((size_t)(tn * 256) + srow) * K + chunk * 8;
  const int t8 = t * 8;

#define GLOAD(SRC, DST) __builtin_amdgcn_global_load_lds(                      \
    (const __attribute__((address_space(1))) void*)(SRC),                      \
    (__attribute__((address_space(3))) void*)(DST), 16, 0, 0)

#define STAGE(T_) do {                                                         \
    GLOAD(gA_t + (size_t)(T_) * 32, &As[(T_) & 3][t8]);                        \
    GLOAD(gB_t + (size_t)(T_) * 32, &Bs[(T_) & 3][t8]);                        \
  } while (0)

  // ---- fragment read offsets: slot = l16 ^ phi(row) ----
  const int ln15 = lane & 15, l16 = lane >> 4;
  const int slA = (l16 ^ ((ln15 >> 1) & 3)) * 8;
  const int aBase = (wr * 64 + ln15) * 32 + slA;
  const int bBase = (wc * 64 + ln15) * 32 + slA;

  f32x4 acc[4][4] = {};
  const int NT = K >> 5;          // even (K multiple of 64)

#define TILE_BODY(T_) do {                                                     \
    const h16* aS = As[(T_) & 3];                                              \
    const h16* bS = Bs[(T_) & 3];                                              \
    h16x8 af[4], bf[4];                                                        \
    _Pragma("unroll")                                                          \
    for (int m = 0; m < 4; ++m) af[m] = *(const h16x8*)(aS + aBase + m * 512); \
    _Pragma("unroll")                                                          \
    for (int n = 0; n < 4; ++n) bf[n] = *(const h16x8*)(bS + bBase + n * 512); \
    _Pragma("unroll")                                                          \
    for (int m = 0; m < 4; ++m)                                                \
      _Pragma("unroll")                                                        \
      for (int n = 0; n < 4; ++n)                                              \
        acc[m][n] = __builtin_amdgcn_mfma_f32_16x16x32_f16(af[m], bf[n],       \
                                                           acc[m][n], 0, 0, 0);\
  } while (0)

  // prologue: stage tiles 0,1; publish.
  STAGE(0); STAGE(1);
  VMCNT(0);
  BARRIER();

  for (int T = 0; T < NT; T += 2) {
    if (T + 2 < NT) STAGE(T + 2);
    if (T + 3 < NT) STAGE(T + 3);
    TILE_BODY(T);
    TILE_BODY(T + 1);
    VMCNT(0);      // stages issued ~2 tile-times ago -> near-free retire
    BARRIER();     // publish slots (T+2)&3,(T+3)&3; free slots T&3,(T+1)&3
  }

  // ---- epilogue: col = ln15 (+n*16) from B side, row = l16*4+j (+m*16) ----
  int colBase = tn * 256 + wc * 64 + ln15;
  int rowBase = tm * 256 + wr * 64 + l16 * 4;
#pragma unroll
  for (int n = 0; n < 4; ++n) {
    float bv = bias[colBase + n * 16];
#pragma unroll
    for (int m = 0; m < 4; ++m) {
#pragma unroll
      for (int j = 0; j < 4; ++j) {
        C[(size_t)(rowBase + m * 16 + j) * N + colBase + n * 16] = acc[m][n][j] + bv;
      }
    }
  }
#undef TILE_BODY
#undef STAGE
#undef GLOAD
}

extern "C" void kernel_launch(void* const* d_in, const int* in_sizes, int n_in,
                              void* d_out, int out_size, void* d_ws, size_t ws_size,
                              hipStream_t stream) {
  const float* A = (const float*)d_in[0];
  const int* Bq = (const int*)d_in[1];
  const int* meta = (const int*)d_in[2];
  const float* s = (const float*)d_in[3];
  const float* bias = (const float*)d_in[4];
  float* C = (float*)d_out;

  const int N = in_sizes[4];
  const int K = (int)(((long long)in_sizes[1] * 16) / N);
  const int M = (int)((long long)in_sizes[0] / K);
  const int sRows = (int)((long long)in_sizes[3] / N);       // K/GS
  const int chunksPerGroup = (K / sRows) / 32;               // GS/32
  const int nBlocksN = N / 256;

  h16* Ah = (h16*)d_ws;                       // M*K f16 = 64 MiB
  h16* Wt = Ah + (size_t)M * K;               // N*K f16 = 32 MiB (W^T, K-major)

  int auxGrid = 2048 + nBlocksN * (K / 32);
  aux_kernel<<<auxGrid, 256, 0, stream>>>(A, Ah, (M * K) / 8, Bq, meta, s, Wt,
                                          K, N, chunksPerGroup, nBlocksN);

  int grid = (M / 256) * (N / 256);
  gemm_kernel<<<grid, 1024, 0, stream>>>(Ah, Wt, bias, C, M, N, K);
}